// Round 1
// 2173.047 us; speedup vs baseline: 1.0829x; 1.0829x over previous
//
#include <hip/hip_runtime.h>
#include <math.h>

// ---------------- problem constants ----------------
#define NROWS   16384      // batch N
#define INF     4096
#define OUTF    4096
#define RANK    409
#define RANK_P  512        // padded rank (zeros beyond 409)
#define K2EXT   416        // 13*32, covers rank 409; cols 409..415 are zero-padded
#define NB      683        // ceil(4096/6) blocks per dim
#define NBLK2   (683*683)  // 466489
#define TOPK    46649      // ceil(466489*0.1)

typedef unsigned short u16;
typedef unsigned int   u32;
typedef unsigned long long u64;

typedef __bf16 v8bf __attribute__((ext_vector_type(8)));
typedef float  v4f  __attribute__((ext_vector_type(4)));

struct SelState { u64 prefix; u64 T; u32 kremain; };

// RNE float -> bf16 (finite inputs)
static __device__ __forceinline__ u16 f2bf(float f) {
    u32 u = __float_as_uint(f);
    u = (u + 0x7FFFu + ((u >> 16) & 1u)) >> 16;
    return (u16)u;
}

static __device__ __forceinline__ void gld_lds16(const void* g, void* l) {
    __builtin_amdgcn_global_load_lds((const __attribute__((address_space(1))) void*)g,
                                     (__attribute__((address_space(3))) void*)l,
                                     16, 0, 0);
}

// ---------------- mask pipeline ----------------

__global__ __launch_bounds__(256) void pooled_kernel(const float* __restrict__ W,
                                                     double* __restrict__ pooled) {
    __shared__ double colsum[INF];
    int bo = blockIdx.x;
    int o0 = bo * 6;
    int cc = min(6, OUTF - o0);
    int tid = threadIdx.x;
    for (int j = tid; j < INF; j += 256) {
        double s = 0.0;
        for (int d = 0; d < cc; d++)
            s += fabs((double)W[(size_t)(o0 + d) * INF + j]);
        colsum[j] = s;
    }
    __syncthreads();
    for (int bi = tid; bi < NB; bi += 256) {
        int i0 = bi * 6;
        int rc = min(6, INF - i0);
        double s = 0.0;
        for (int d = 0; d < rc; d++) s += colsum[i0 + d];
        pooled[(size_t)bo * NB + bi] = s / (double)(rc * cc);
    }
}

__global__ void init_select(u32* hist, SelState* st) {
    int t = blockIdx.x * 256 + threadIdx.x;
    if (t < 2048) hist[t] = 0;
    if (t == 0) { st->prefix = 0ull; st->T = 0ull; st->kremain = TOPK; }
}

__global__ __launch_bounds__(256) void hist_kernel(const double* __restrict__ pooled,
                                                   u32* __restrict__ hist,
                                                   const SelState* __restrict__ st,
                                                   int shift, int hs, int nbins, int pass) {
    __shared__ u32 h[2048];
    int tid = threadIdx.x;
    for (int i = tid; i < nbins; i += 256) h[i] = 0;
    __syncthreads();
    int idx = blockIdx.x * 256 + tid;
    if (idx < NBLK2) {
        u64 bits = (u64)__double_as_longlong(pooled[idx]);
        bool ok = (pass == 0) || ((bits >> hs) == st->prefix);
        if (ok) atomicAdd(&h[(u32)((bits >> shift) & (u64)(nbins - 1))], 1u);
    }
    __syncthreads();
    for (int i = tid; i < nbins; i += 256)
        if (h[i]) atomicAdd(&hist[i], h[i]);
}

__global__ __launch_bounds__(256) void scan_kernel(u32* __restrict__ hist,
                                                   SelState* __restrict__ st,
                                                   int nbins, int width, int is_last) {
    __shared__ u32 h[2048];
    int tid = threadIdx.x;
    for (int i = tid; i < nbins; i += 256) h[i] = hist[i];
    __syncthreads();
    if (tid == 0) {
        u64 kr = st->kremain;
        u64 accum = 0; int chosen = 0; u64 newk = kr;
        for (int d = nbins - 1; d >= 0; d--) {
            u64 c = h[d];
            if (accum + c >= kr) { chosen = d; newk = kr - accum; break; }
            accum += c;
        }
        st->prefix = (st->prefix << width) | (u64)chosen;
        st->kremain = (u32)newk;
        if (is_last) st->T = st->prefix;
    }
    __syncthreads();
    for (int i = tid; i < nbins; i += 256) hist[i] = 0;   // ready for next pass
}

// Masked weight -> bf16, row-major (o, i). flag = pooled(bi,bo) >= T
__global__ __launch_bounds__(256) void build_wmb(const float* __restrict__ W,
                                                 const double* __restrict__ pooled,
                                                 const SelState* __restrict__ st,
                                                 u16* __restrict__ wmb) {
    size_t idx = ((size_t)blockIdx.x * 256 + threadIdx.x) * 4;
    int o = (int)(idx >> 12);
    int i = (int)(idx & 4095);
    float4 w = *(const float4*)(W + idx);
    u64 T = st->T;
    int bo = o / 6;
    float wv[4] = {w.x, w.y, w.z, w.w};
    u16 rr[4];
#pragma unroll
    for (int e = 0; e < 4; e++) {
        int bi = (i + e) / 6;
        u64 b = (u64)__double_as_longlong(pooled[(size_t)bo * NB + bi]);
        rr[e] = (b >= T) ? f2bf(wv[e]) : (u16)0;
    }
    ushort4 r; r.x = rr[0]; r.y = rr[1]; r.z = rr[2]; r.w = rr[3];
    *(ushort4*)(wmb + idx) = r;
}

// ---------------- gate + x->bf16 (fused) ----------------
__global__ __launch_bounds__(256) void gate_xb(const float* __restrict__ X,
                                               const float* __restrict__ gw,
                                               const float* __restrict__ gb,
                                               u16* __restrict__ XB,
                                               float* __restrict__ G) {
    __shared__ float red[256];
    int row = blockIdx.x, tid = threadIdx.x;
    const float* xr = X + (size_t)row * INF;
    u16* xb = XB + (size_t)row * INF;
    float dot = 0.f;
#pragma unroll
    for (int jj = 0; jj < 4; jj++) {
        int col = jj * 1024 + tid * 4;
        float4 v = *(const float4*)(xr + col);
        float4 w = *(const float4*)(gw + col);
        dot += v.x * w.x + v.y * w.y + v.z * w.z + v.w * w.w;
        ushort4 o4; o4.x = f2bf(v.x); o4.y = f2bf(v.y); o4.z = f2bf(v.z); o4.w = f2bf(v.w);
        *(ushort4*)(xb + col) = o4;
    }
    red[tid] = dot;
    __syncthreads();
    for (int s = 128; s > 0; s >>= 1) {
        if (tid < s) red[tid] += red[tid + s];
        __syncthreads();
    }
    if (tid == 0) {
        float z = red[0] + gb[0];
        G[row] = 1.f / (1.f + expf(-z));
    }
}

// ---------------- transpose+pack fp32 -> bf16, zero-pad ----------------
__global__ void transpose_pack(const float* __restrict__ src, u16* __restrict__ dst,
                               int sr, int sc, int dr, int dc) {
    __shared__ float tile[32][33];
    int i0 = blockIdx.x * 32;   // src row base / dst col base
    int j0 = blockIdx.y * 32;   // src col base / dst row base
    for (int yy = threadIdx.y; yy < 32; yy += 8) {
        int si = i0 + yy, sj = j0 + threadIdx.x;
        tile[yy][threadIdx.x] = (si < sr && sj < sc) ? src[(size_t)si * sc + sj] : 0.f;
    }
    __syncthreads();
    for (int yy = threadIdx.y; yy < 32; yy += 8) {
        int dj = j0 + yy, di = i0 + threadIdx.x;
        if (dj < dr && di < dc) dst[(size_t)dj * dc + di] = f2bf(tile[threadIdx.x][yy]);
    }
}

// ---------------- NT bf16 MFMA GEMM, double-buffered stage-ahead ----------------
// C[M,N] = A1[M,K1] * B1[N,K1]^T  (+ optional second accumulator over A2/B2, K2EXT)
// 128x128 tile, BK=32, 4 waves 2x2, 4x4 frags of 16x16x32 MFMA per wave.
// Loop: STAGE(tile t+1 -> buf^1) issued BEFORE compute(tile t, buf), one
// __syncthreads (vmcnt0+barrier) per K-step -> load latency hides under MFMA.
// XCD-aware bijective block swizzle (nwg % 8 == 0 for both launches).
// EPI 0: TOUT = bf16(acc)              [t = x @ lr1t, N=512]
// EPI 2: OUT  = g*(acc+SB) + (1-g)*(acc2+LB)   [fused sparse+low, N=4096]
template <int EPI>
__global__ __launch_bounds__(256, 2) void gemm_db(const u16* __restrict__ A1,
                                                  const u16* __restrict__ B1,
                                                  const u16* __restrict__ A2,
                                                  const u16* __restrict__ B2,
                                                  float* __restrict__ OUT,
                                                  u16* __restrict__ TOUT,
                                                  const float* __restrict__ G,
                                                  const float* __restrict__ SB,
                                                  const float* __restrict__ LB) {
    constexpr int K1   = INF;                       // 4096, also lda/ldb of segment 1
    constexpr int K2   = (EPI == 2) ? K2EXT : 0;    // 416 (13 tiles) or 0
    constexpr int LD2  = RANK_P;                    // 512 leading dim of segment 2
    constexpr int NN   = (EPI == 0) ? RANK_P : OUTF;
    constexpr int NBXL = (EPI == 0) ? 2 : 5;        // log2(NN/128)
    constexpr int NT1  = K1 / 32;
    constexpr int NT2  = K2 / 32;
    constexpr int NT   = NT1 + NT2;

    __shared__ __align__(16) u16 As[2][128 * 32];
    __shared__ __align__(16) u16 Bs[2][128 * 32];

    // XCD-aware bijective swizzle (gridDim.x % 8 == 0)
    int ord = blockIdx.x;
    int cpx = gridDim.x >> 3;
    int swz = (ord & 7) * cpx + (ord >> 3);
    int bx = swz & ((1 << NBXL) - 1);
    int by = swz >> NBXL;
    int m0 = by * 128, n0 = bx * 128;

    int tid  = threadIdx.x;
    int wave = tid >> 6, lane = tid & 63;
    int quad = lane >> 4, lrow = lane & 15;
    int wm = wave >> 1, wn = wave & 1;

    int c0 = tid, c1 = tid + 256;
    int rA0 = c0 >> 2, e0 = (c0 & 3) * 8;   // row, element offset of 16B chunk
    int rA1 = c1 >> 2, e1 = (c1 & 3) * 8;
    u32 ldsOff0 = (u32)(wave * 64) * 16u;          // wave-uniform LDS byte base
    u32 ldsOff1 = (u32)(wave * 64 + 256) * 16u;

    v4f acc[4][4];
    v4f acc2[4][4];
#pragma unroll
    for (int i = 0; i < 4; i++)
#pragma unroll
        for (int j = 0; j < 4; j++) {
            acc[i][j] = (v4f)0.f;
            if (EPI == 2) acc2[i][j] = (v4f)0.f;
        }

    // per-thread global source pointers for the NEXT tile to stage
    const u16* pa0 = A1 + (size_t)(m0 + rA0) * K1 + e0;
    const u16* pa1 = A1 + (size_t)(m0 + rA1) * K1 + e1;
    const u16* pb0 = B1 + (size_t)(n0 + rA0) * K1 + e0;
    const u16* pb1 = B1 + (size_t)(n0 + rA1) * K1 + e1;

    auto STAGE = [&](int buf) {
        gld_lds16(pa0, (char*)&As[buf][0] + ldsOff0);
        gld_lds16(pa1, (char*)&As[buf][0] + ldsOff1);
        gld_lds16(pb0, (char*)&Bs[buf][0] + ldsOff0);
        gld_lds16(pb1, (char*)&Bs[buf][0] + ldsOff1);
    };
    auto ADV = [&](int tnext) {
        if (EPI == 2 && tnext == NT1) {             // switch to segment 2 bases
            pa0 = A2 + (size_t)(m0 + rA0) * LD2 + e0;
            pa1 = A2 + (size_t)(m0 + rA1) * LD2 + e1;
            pb0 = B2 + (size_t)(n0 + rA0) * LD2 + e0;
            pb1 = B2 + (size_t)(n0 + rA1) * LD2 + e1;
        } else {
            pa0 += 32; pa1 += 32; pb0 += 32; pb1 += 32;
        }
    };
    auto COMPUTE = [&](int buf, v4f (&ac)[4][4]) {
        v8bf af[4], bv[4];
#pragma unroll
        for (int i = 0; i < 4; i++)
            af[i] = *(const v8bf*)(&As[buf][(wm * 64 + i * 16 + lrow) * 32 + quad * 8]);
#pragma unroll
        for (int j = 0; j < 4; j++)
            bv[j] = *(const v8bf*)(&Bs[buf][(wn * 64 + j * 16 + lrow) * 32 + quad * 8]);
#pragma unroll
        for (int i = 0; i < 4; i++)
#pragma unroll
            for (int j = 0; j < 4; j++)
                ac[i][j] = __builtin_amdgcn_mfma_f32_16x16x32_bf16(af[i], bv[j], ac[i][j], 0, 0, 0);
    };

    // prologue: tile 0 -> buf 0
    STAGE(0);
    ADV(1);
    __syncthreads();                                // vmcnt(0) + barrier

    for (int t = 0; t < NT - 1; ++t) {
        int cur = t & 1;
        STAGE(cur ^ 1);                             // issue tile t+1 loads early
        ADV(t + 2);
        if (EPI == 2 && t >= NT1) COMPUTE(cur, acc2);
        else                      COMPUTE(cur, acc);
        __syncthreads();                            // drain stage + barrier
    }
    {
        int cur = (NT - 1) & 1;
        if (EPI == 2 && NT - 1 >= NT1) COMPUTE(cur, acc2);
        else                           COMPUTE(cur, acc);
    }

    // epilogue
#pragma unroll
    for (int i = 0; i < 4; i++) {
#pragma unroll
        for (int r = 0; r < 4; r++) {
            int grow = m0 + wm * 64 + i * 16 + quad * 4 + r;
            float gv = 0.f;
            if (EPI == 2) gv = G[grow];
#pragma unroll
            for (int j = 0; j < 4; j++) {
                int gcol = n0 + wn * 64 + j * 16 + lrow;
                size_t idx = (size_t)grow * NN + gcol;
                if (EPI == 0) {
                    TOUT[idx] = f2bf(acc[i][j][r]);
                } else {
                    OUT[idx] = gv * (acc[i][j][r] + SB[gcol])
                             + (1.f - gv) * (acc2[i][j][r] + LB[gcol]);
                }
            }
        }
    }
}

// ---------------- launcher ----------------
extern "C" void kernel_launch(void* const* d_in, const int* in_sizes, int n_in,
                              void* d_out, int out_size, void* d_ws, size_t ws_size,
                              hipStream_t stream) {
    const float* X   = (const float*)d_in[0];   // (16384, 4096)
    const float* GW  = (const float*)d_in[1];   // (4096, 1)
    const float* GB  = (const float*)d_in[2];   // (1,)
    const float* W   = (const float*)d_in[3];   // (4096, 4096)
    const float* SBv = (const float*)d_in[4];   // (4096,)
    const float* LR1 = (const float*)d_in[5];   // (4096, 409)
    const float* LR2 = (const float*)d_in[6];   // (409, 4096)
    const float* LBv = (const float*)d_in[7];   // (4096,)
    float* OUT = (float*)d_out;

    // workspace layout (bytes)
    const size_t OFF_POOLED = 0;                                  // 466489 * 8
    const size_t OFF_HIST   = 3 * 1024 * 1024 + 768 * 1024;       // 3.75 MB mark
    const size_t OFF_STATE  = OFF_HIST + 2048 * 4;
    const size_t OFF_XB     = 4ull * 1024 * 1024;                 // 134 MB
    const size_t OFF_WMB    = OFF_XB + (size_t)NROWS * INF * 2;   // 33.5 MB
    const size_t OFF_LR1T   = OFF_WMB + (size_t)OUTF * INF * 2;   // 4 MB
    const size_t OFF_LR2T   = OFF_LR1T + (size_t)RANK_P * INF * 2;
    const size_t OFF_T      = OFF_LR2T + (size_t)OUTF * RANK_P * 2; // 16 MB
    const size_t OFF_G      = OFF_T + (size_t)NROWS * RANK_P * 2;
    const size_t NEED       = OFF_G + (size_t)NROWS * 4;
    if (ws_size < NEED) return;  // visible failure (poison retained)

    char* ws = (char*)d_ws;
    double*   pooled = (double*)(ws + OFF_POOLED);
    u32*      hist   = (u32*)(ws + OFF_HIST);
    SelState* st     = (SelState*)(ws + OFF_STATE);
    u16*      XB     = (u16*)(ws + OFF_XB);
    u16*      WMB    = (u16*)(ws + OFF_WMB);
    u16*      LR1T   = (u16*)(ws + OFF_LR1T);
    u16*      LR2T   = (u16*)(ws + OFF_LR2T);
    u16*      Tbuf   = (u16*)(ws + OFF_T);
    float*    G      = (float*)(ws + OFF_G);

    // 1) pooled block means (fp64, deterministic)
    pooled_kernel<<<NB, 256, 0, stream>>>(W, pooled);

    // 2) exact 64-bit radix select of k-th largest pooled value
    init_select<<<8, 256, 0, stream>>>(hist, st);
    const int histGrid = (NBLK2 + 255) / 256;
    const int sh[6]   = {53, 42, 31, 20, 9, 0};
    const int wd[6]   = {11, 11, 11, 11, 11, 9};
    for (int p = 0; p < 6; p++) {
        int nb = 1 << wd[p];
        hist_kernel<<<histGrid, 256, 0, stream>>>(pooled, hist, st, sh[p], sh[p] + wd[p], nb, p);
        scan_kernel<<<1, 256, 0, stream>>>(hist, st, nb, wd[p], (p == 5) ? 1 : 0);
    }

    // 3) packs
    build_wmb<<<(OUTF * INF) / (256 * 4), 256, 0, stream>>>(W, pooled, st, WMB);
    gate_xb<<<NROWS, 256, 0, stream>>>(X, GW, GB, XB, G);
    {
        dim3 b(32, 8);
        transpose_pack<<<dim3(INF / 32, RANK_P / 32), b, 0, stream>>>(LR1, LR1T, INF, RANK, RANK_P, INF);
        transpose_pack<<<dim3(RANK_P / 32, OUTF / 32), b, 0, stream>>>(LR2, LR2T, RANK, OUTF, OUTF, RANK_P);
    }

    // 4) GEMMs
    // t = x @ lr1   (M=16384, N=512, K=4096) -> bf16
    gemm_db<0><<<(RANK_P / 128) * (NROWS / 128), 256, 0, stream>>>(
        XB, LR1T, nullptr, nullptr, nullptr, Tbuf, nullptr, nullptr, nullptr);
    // out = g*(x@Wm^T + sb) + (1-g)*(t@lr2 + lb)   (fused, dual accumulator)
    gemm_db<2><<<(OUTF / 128) * (NROWS / 128), 256, 0, stream>>>(
        XB, WMB, Tbuf, LR2T, OUT, nullptr, G, SBv, LBv);
}

// Round 4
// 1646.680 us; speedup vs baseline: 1.4290x; 1.3197x over previous
//
#include <hip/hip_runtime.h>
#include <math.h>

// ---------------- problem constants ----------------
#define NROWS   16384      // batch N
#define INF     4096
#define OUTF    4096
#define RANK    409
#define RANK_P  512        // padded rank for gemm0 N (zeros beyond 409)
#define KSEG2   416        // 13*32, stored low-rank K segment (cols 409..415 zero)
#define KCAT    4512       // 4096 + 416 concatenated K
#define NT_BIG  141        // 4512/32
#define NT_G0   128        // 4096/32
#define NB      683        // ceil(4096/6) blocks per dim
#define NBLK2   (683*683)  // 466489
#define TOPK    46649      // ceil(466489*0.1)

typedef unsigned short u16;
typedef unsigned int   u32;
typedef unsigned long long u64;

typedef __bf16 v8bf __attribute__((ext_vector_type(8)));
typedef float  v4f  __attribute__((ext_vector_type(4)));

struct SelState { u64 prefix; u64 T; u32 kremain; };

// RNE float -> bf16 (finite inputs)
static __device__ __forceinline__ u16 f2bf(float f) {
    u32 u = __float_as_uint(f);
    u = (u + 0x7FFFu + ((u >> 16) & 1u)) >> 16;
    return (u16)u;
}

static __device__ __forceinline__ void gld_lds16(const void* g, void* l) {
    __builtin_amdgcn_global_load_lds((const __attribute__((address_space(1))) void*)g,
                                     (__attribute__((address_space(3))) void*)l,
                                     16, 0, 0);
}

// ---------------- mask pipeline ----------------

__global__ __launch_bounds__(256) void pooled_kernel(const float* __restrict__ W,
                                                     double* __restrict__ pooled) {
    __shared__ double colsum[INF];
    int bo = blockIdx.x;
    int o0 = bo * 6;
    int cc = min(6, OUTF - o0);
    int tid = threadIdx.x;
    for (int j = tid; j < INF; j += 256) {
        double s = 0.0;
        for (int d = 0; d < cc; d++)
            s += fabs((double)W[(size_t)(o0 + d) * INF + j]);
        colsum[j] = s;
    }
    __syncthreads();
    for (int bi = tid; bi < NB; bi += 256) {
        int i0 = bi * 6;
        int rc = min(6, INF - i0);
        double s = 0.0;
        for (int d = 0; d < rc; d++) s += colsum[i0 + d];
        pooled[(size_t)bo * NB + bi] = s / (double)(rc * cc);
    }
}

__global__ void init_select(u32* hist, SelState* st) {
    int t = blockIdx.x * 256 + threadIdx.x;
    if (t < 2048) hist[t] = 0;
    if (t == 0) { st->prefix = 0ull; st->T = 0ull; st->kremain = TOPK; }
}

__global__ __launch_bounds__(256) void hist_kernel(const double* __restrict__ pooled,
                                                   u32* __restrict__ hist,
                                                   const SelState* __restrict__ st,
                                                   int shift, int hs, int nbins, int pass) {
    __shared__ u32 h[2048];
    int tid = threadIdx.x;
    for (int i = tid; i < nbins; i += 256) h[i] = 0;
    __syncthreads();
    int idx = blockIdx.x * 256 + tid;
    if (idx < NBLK2) {
        u64 bits = (u64)__double_as_longlong(pooled[idx]);
        bool ok = (pass == 0) || ((bits >> hs) == st->prefix);
        if (ok) atomicAdd(&h[(u32)((bits >> shift) & (u64)(nbins - 1))], 1u);
    }
    __syncthreads();
    for (int i = tid; i < nbins; i += 256)
        if (h[i]) atomicAdd(&hist[i], h[i]);
}

// Parallel suffix-sum scan (replaces tid==0 serial 2048-iter loop).
__global__ __launch_bounds__(256) void scan_kernel(u32* __restrict__ hist,
                                                   SelState* __restrict__ st,
                                                   int nbins, int width, int is_last) {
    __shared__ u32 sA[2048], sB[2048];
    __shared__ u32 kr_sh;
    __shared__ int chosen_sh;
    int tid = threadIdx.x;
    if (tid == 0) { kr_sh = st->kremain; chosen_sh = 0; }
    for (int i = tid; i < nbins; i += 256) sA[i] = hist[i];
    __syncthreads();
    u32* src = sA; u32* dst = sB;
    for (int off = 1; off < nbins; off <<= 1) {
        for (int i = tid; i < nbins; i += 256)
            dst[i] = src[i] + ((i + off < nbins) ? src[i + off] : 0u);
        __syncthreads();
        u32* tmp = src; src = dst; dst = tmp;
    }
    // src[i] = sum_{d>=i} h[d]  (non-increasing in i)
    u32 kr = kr_sh;
    for (int i = tid; i < nbins; i += 256) {
        u32 s = src[i];
        u32 snext = (i + 1 < nbins) ? src[i + 1] : 0u;
        if (s >= kr && snext < kr) chosen_sh = i;   // unique writer
    }
    __syncthreads();
    if (tid == 0) {
        int chosen = chosen_sh;
        u32 accum = (chosen + 1 < nbins) ? src[chosen + 1] : 0u;
        st->prefix = (st->prefix << width) | (u64)chosen;
        st->kremain = kr - accum;
        if (is_last) st->T = st->prefix;
    }
    __syncthreads();
    for (int i = tid; i < nbins; i += 256) hist[i] = 0;   // ready for next pass
}

// Masked weight -> bf16 into WMBE segment 1 (row stride KCAT).
__global__ __launch_bounds__(256) void build_wmb(const float* __restrict__ W,
                                                 const double* __restrict__ pooled,
                                                 const SelState* __restrict__ st,
                                                 u16* __restrict__ wmb) {
    size_t lin = ((size_t)blockIdx.x * 256 + threadIdx.x) * 4;
    int o = (int)(lin >> 12);
    int i = (int)(lin & 4095);
    float4 w = *(const float4*)(W + lin);
    u64 T = st->T;
    int bo = o / 6;
    float wv[4] = {w.x, w.y, w.z, w.w};
    u16 rr[4];
#pragma unroll
    for (int e = 0; e < 4; e++) {
        int bi = (i + e) / 6;
        u64 b = (u64)__double_as_longlong(pooled[(size_t)bo * NB + bi]);
        rr[e] = (b >= T) ? f2bf(wv[e]) : (u16)0;
    }
    ushort4 r; r.x = rr[0]; r.y = rr[1]; r.z = rr[2]; r.w = rr[3];
    *(ushort4*)(wmb + (size_t)o * KCAT + i) = r;
}

// ---------------- gate + x->bf16 (fused); writes XBE segment 1 UNSCALED ----------------
__global__ __launch_bounds__(256) void gate_xb(const float* __restrict__ X,
                                               const float* __restrict__ gw,
                                               const float* __restrict__ gb,
                                               u16* __restrict__ XBE,
                                               float* __restrict__ G) {
    __shared__ float red[256];
    int row = blockIdx.x, tid = threadIdx.x;
    const float* xr = X + (size_t)row * INF;
    u16* xb = XBE + (size_t)row * KCAT;
    float dot = 0.f;
#pragma unroll
    for (int jj = 0; jj < 4; jj++) {
        int col = jj * 1024 + tid * 4;
        float4 v = *(const float4*)(xr + col);
        float4 w = *(const float4*)(gw + col);
        dot += v.x * w.x + v.y * w.y + v.z * w.z + v.w * w.w;
        ushort4 o4; o4.x = f2bf(v.x); o4.y = f2bf(v.y); o4.z = f2bf(v.z); o4.w = f2bf(v.w);
        *(ushort4*)(xb + col) = o4;
    }
    red[tid] = dot;
    __syncthreads();
    for (int s = 128; s > 0; s >>= 1) {
        if (tid < s) red[tid] += red[tid + s];
        __syncthreads();
    }
    if (tid == 0) {
        float z = red[0] + gb[0];
        G[row] = 1.f / (1.f + expf(-z));
    }
}

// ---------------- in-place scale of XBE segment 1 by g[row] ----------------
static __device__ __forceinline__ u32 scale2bf(u32 w, float g) {
    float lo = __uint_as_float(w << 16) * g;
    float hi = __uint_as_float(w & 0xFFFF0000u) * g;
    return (u32)f2bf(lo) | ((u32)f2bf(hi) << 16);
}

__global__ __launch_bounds__(256) void rescale_rows(u16* __restrict__ XBE,
                                                    const float* __restrict__ G) {
    int row = blockIdx.x;
    float g = G[row];
    u16* p = XBE + (size_t)row * KCAT + threadIdx.x * 16;   // 16 elems/thread
    uint4 a = *(const uint4*)p;
    uint4 b = *(const uint4*)(p + 8);
    a.x = scale2bf(a.x, g); a.y = scale2bf(a.y, g);
    a.z = scale2bf(a.z, g); a.w = scale2bf(a.w, g);
    b.x = scale2bf(b.x, g); b.y = scale2bf(b.y, g);
    b.z = scale2bf(b.z, g); b.w = scale2bf(b.w, g);
    *(uint4*)p = a;
    *(uint4*)(p + 8) = b;
}

// ---------------- transpose+pack fp32 -> bf16, zero-pad, strided dst ----------------
// dst[(j)*ldd + col0 + i] = (i < sr && j < sc) ? bf16(src[i][j]) : 0  for j<dr, i<dc
__global__ void transpose_pack(const float* __restrict__ src, u16* __restrict__ dst,
                               int sr, int sc, int dr, int dc, int ldd, int col0) {
    __shared__ float tile[32][33];
    int i0 = blockIdx.x * 32;   // src row base / dst col base
    int j0 = blockIdx.y * 32;   // src col base / dst row base
    for (int yy = threadIdx.y; yy < 32; yy += 8) {
        int si = i0 + yy, sj = j0 + threadIdx.x;
        tile[yy][threadIdx.x] = (si < sr && sj < sc) ? src[(size_t)si * sc + sj] : 0.f;
    }
    __syncthreads();
    for (int yy = threadIdx.y; yy < 32; yy += 8) {
        int dj = j0 + yy, di = i0 + threadIdx.x;
        if (dj < dr && di < dc) dst[(size_t)dj * ldd + col0 + di] = f2bf(tile[threadIdx.x][yy]);
    }
}

// ---------------- NT bf16 MFMA GEMM, double-buffered stage-ahead ----------------
// C[M,N] = A[M,K] * B[N,K]^T, K = NT*32, row strides LDA/LDB.
// 128x128 tile, BK=32, 4 waves 2x2, 4x4 frags of 16x16x32 MFMA, SINGLE accumulator
// (64 AGPR + ~100 VGPR -> 3 waves/SIMD). Proven loop structure (round-1 verified):
//   iteration t: STAGE(t+1 -> buf^1); COMPUTE(t, buf); __syncthreads()
// EPI 0: XBE seg2 [grow*KCAT + 4096 + gcol] = bf16((1-g)*acc), gcol<416
// EPI 2: OUT = acc + g*SB + (1-g)*LB        (acc already = g*s + (1-g)*l)
template <int EPI, int NT, int LDA, int LDB, int NN>
__global__ __launch_bounds__(256, 3) void gemm_db(const u16* __restrict__ A,
                                                  const u16* __restrict__ B,
                                                  float* __restrict__ OUT,
                                                  u16* __restrict__ TOUT,
                                                  const float* __restrict__ G,
                                                  const float* __restrict__ SB,
                                                  const float* __restrict__ LB) {
    constexpr int NBXL = (NN == 512) ? 2 : 5;       // log2(NN/128)
    __shared__ __align__(16) u16 As[2][128 * 32];
    __shared__ __align__(16) u16 Bs[2][128 * 32];

    // XCD-aware bijective swizzle (gridDim.x % 8 == 0 for both launches)
    int ord = blockIdx.x;
    int cpx = gridDim.x >> 3;
    int swz = (ord & 7) * cpx + (ord >> 3);
    int bx = swz & ((1 << NBXL) - 1);
    int by = swz >> NBXL;
    int m0 = by * 128, n0 = bx * 128;

    int tid  = threadIdx.x;
    int wave = tid >> 6, lane = tid & 63;
    int quad = lane >> 4, lrow = lane & 15;
    int wm = wave >> 1, wn = wave & 1;

    int c0 = tid, c1 = tid + 256;
    int rA0 = c0 >> 2, e0 = (c0 & 3) * 8;
    int rA1 = c1 >> 2, e1 = (c1 & 3) * 8;
    u32 ldsOff0 = (u32)(wave * 64) * 16u;
    u32 ldsOff1 = (u32)(wave * 64 + 256) * 16u;

    const u16* pa0 = A + (size_t)(m0 + rA0) * LDA + e0;
    const u16* pa1 = A + (size_t)(m0 + rA1) * LDA + e1;
    const u16* pb0 = B + (size_t)(n0 + rA0) * LDB + e0;
    const u16* pb1 = B + (size_t)(n0 + rA1) * LDB + e1;

    v4f acc[4][4];
#pragma unroll
    for (int i = 0; i < 4; i++)
#pragma unroll
        for (int j = 0; j < 4; j++) acc[i][j] = (v4f)0.f;

    auto STAGE = [&](int buf) {
        gld_lds16(pa0, (char*)&As[buf][0] + ldsOff0);
        gld_lds16(pa1, (char*)&As[buf][0] + ldsOff1);
        gld_lds16(pb0, (char*)&Bs[buf][0] + ldsOff0);
        gld_lds16(pb1, (char*)&Bs[buf][0] + ldsOff1);
        pa0 += 32; pa1 += 32; pb0 += 32; pb1 += 32;
    };
    auto COMPUTE = [&](int buf) {
        v8bf af[4], bv[4];
#pragma unroll
        for (int i = 0; i < 4; i++)
            af[i] = *(const v8bf*)(&As[buf][(wm * 64 + i * 16 + lrow) * 32 + quad * 8]);
#pragma unroll
        for (int j = 0; j < 4; j++)
            bv[j] = *(const v8bf*)(&Bs[buf][(wn * 64 + j * 16 + lrow) * 32 + quad * 8]);
#pragma unroll
        for (int i = 0; i < 4; i++)
#pragma unroll
            for (int j = 0; j < 4; j++)
                acc[i][j] = __builtin_amdgcn_mfma_f32_16x16x32_bf16(af[i], bv[j], acc[i][j], 0, 0, 0);
    };

    // prologue: tile 0 -> buf 0
    STAGE(0);
    __syncthreads();                                // vmcnt(0) + barrier

    for (int t = 0; t < NT - 1; ++t) {
        int cur = t & 1;
        STAGE(cur ^ 1);                             // issue tile t+1 loads early
        COMPUTE(cur);
        __syncthreads();                            // drain stage + barrier
    }
    COMPUTE((NT - 1) & 1);

    // epilogue
#pragma unroll
    for (int i = 0; i < 4; i++) {
#pragma unroll
        for (int r = 0; r < 4; r++) {
            int grow = m0 + wm * 64 + i * 16 + quad * 4 + r;
            float gv = G[grow];
#pragma unroll
            for (int j = 0; j < 4; j++) {
                int gcol = n0 + wn * 64 + j * 16 + lrow;
                if (EPI == 0) {
                    if (gcol < KSEG2)
                        TOUT[(size_t)grow * KCAT + 4096 + gcol] =
                            f2bf((1.f - gv) * acc[i][j][r]);
                } else {
                    OUT[(size_t)grow * NN + gcol] =
                        acc[i][j][r] + gv * SB[gcol] + (1.f - gv) * LB[gcol];
                }
            }
        }
    }
}

// ---------------- launcher ----------------
extern "C" void kernel_launch(void* const* d_in, const int* in_sizes, int n_in,
                              void* d_out, int out_size, void* d_ws, size_t ws_size,
                              hipStream_t stream) {
    const float* X   = (const float*)d_in[0];   // (16384, 4096)
    const float* GW  = (const float*)d_in[1];   // (4096, 1)
    const float* GB  = (const float*)d_in[2];   // (1,)
    const float* W   = (const float*)d_in[3];   // (4096, 4096)
    const float* SBv = (const float*)d_in[4];   // (4096,)
    const float* LR1 = (const float*)d_in[5];   // (4096, 409)
    const float* LR2 = (const float*)d_in[6];   // (409, 4096)
    const float* LBv = (const float*)d_in[7];   // (4096,)
    float* OUT = (float*)d_out;

    // workspace layout (bytes)
    const size_t OFF_POOLED = 0;                                   // 466489*8 = 3.73 MB
    const size_t OFF_HIST   = 3932160;                             // 3.75 MB
    const size_t OFF_STATE  = OFF_HIST + 2048 * 4;
    const size_t OFF_LR1T   = 4ull * 1024 * 1024;                  // 512*4096*2 = 4 MB
    const size_t OFF_XBE    = OFF_LR1T + (size_t)RANK_P * INF * 2; // 8 MB
    const size_t OFF_WMBE   = OFF_XBE + (size_t)NROWS * KCAT * 2;  // +147.8 MB
    const size_t OFF_G      = OFF_WMBE + (size_t)OUTF * KCAT * 2;  // +37.0 MB
    const size_t NEED       = OFF_G + (size_t)NROWS * 4;           // ~193.3 MB
    if (ws_size < NEED) return;  // visible failure (poison retained)

    char* ws = (char*)d_ws;
    double*   pooled = (double*)(ws + OFF_POOLED);
    u32*      hist   = (u32*)(ws + OFF_HIST);
    SelState* st     = (SelState*)(ws + OFF_STATE);
    u16*      LR1T   = (u16*)(ws + OFF_LR1T);
    u16*      XBE    = (u16*)(ws + OFF_XBE);
    u16*      WMBE   = (u16*)(ws + OFF_WMBE);
    float*    G      = (float*)(ws + OFF_G);

    // 1) pooled block means (fp64, deterministic)
    pooled_kernel<<<NB, 256, 0, stream>>>(W, pooled);

    // 2) exact 64-bit radix select of k-th largest pooled value
    init_select<<<8, 256, 0, stream>>>(hist, st);
    const int histGrid = (NBLK2 + 255) / 256;
    const int sh[6]   = {53, 42, 31, 20, 9, 0};
    const int wd[6]   = {11, 11, 11, 11, 11, 9};
    for (int p = 0; p < 6; p++) {
        int nb = 1 << wd[p];
        hist_kernel<<<histGrid, 256, 0, stream>>>(pooled, hist, st, sh[p], sh[p] + wd[p], nb, p);
        scan_kernel<<<1, 256, 0, stream>>>(hist, st, nb, wd[p], (p == 5) ? 1 : 0);
    }

    // 3) packs
    build_wmb<<<(OUTF * INF) / (256 * 4), 256, 0, stream>>>(W, pooled, st, WMBE);
    {
        dim3 b(32, 8);
        // LR1T (512 x 4096): B for gemm0
        transpose_pack<<<dim3(INF / 32, RANK_P / 32), b, 0, stream>>>(
            LR1, LR1T, INF, RANK, RANK_P, INF, INF, 0);
        // WMBE segment 2 (4096 rows x 416 cols at col 4096): lr2^T zero-padded
        transpose_pack<<<dim3(KSEG2 / 32, OUTF / 32), b, 0, stream>>>(
            LR2, WMBE, RANK, OUTF, OUTF, KSEG2, KCAT, 4096);
    }
    gate_xb<<<NROWS, 256, 0, stream>>>(X, GW, GB, XBE, G);

    // 4) gemm0: t = x @ lr1 (M=16384, N=512, K=4096); writes XBE seg2 = bf16((1-g)*t)
    //    (reads only cols < 4096 of XBE, writes only cols >= 4096 -> no intra-kernel alias)
    gemm_db<0, NT_G0, KCAT, INF, RANK_P>
        <<<(RANK_P / 128) * (NROWS / 128), 256, 0, stream>>>(
        XBE, LR1T, nullptr, XBE, G, nullptr, nullptr);

    // 5) scale XBE seg1 rows by g  (seg1 becomes bf16(g*x))
    rescale_rows<<<NROWS, 256, 0, stream>>>(XBE, G);

    // 6) fused big GEMM over concatenated K=4512:
    //    acc = g*(x@Wm^T) + (1-g)*(t@lr2);  OUT = acc + g*SB + (1-g)*LB
    gemm_db<2, NT_BIG, KCAT, KCAT, OUTF>
        <<<(OUTF / 128) * (NROWS / 128), 256, 0, stream>>>(
        XBE, WMBE, OUT, nullptr, G, SBv, LBv);
}